// Round 1
// baseline (1509.499 us; speedup 1.0000x reference)
//
#include <hip/hip_runtime.h>

#define BROWS 131072
#define DD 64
#define INF 128
#define NOUT 8
#define NITER 50

// mats layout (floats) inside ws, after biasT
#define OFF_W1S   0                  // [128][64]  W1s[k*64+j] = W1[j][k]
#define OFF_UWS   (8192)             // [64][64]   Uws[k*64+j] = Uw[j][k]
#define OFF_WINVS (8192+4096)        // [64][64]   Winvs[k*64+j] = Winv[j][k]
#define OFF_RMS   (8192+2*4096)      // [64][64]   Rms[k*64+j] = 2*Winv[j][k] - d(k,j)
#define OFF_WSS   (8192+3*4096)      // [64][64]   Wss[k*64+j] = W[j][k]
#define OFF_PWS   (8192+4*4096)      // [64][8]    Pws[j*8+o]  = Pw[o][j]

// ---------------------------------------------------------------------------
// Prep: build W = 0.9I - Aw^T Aw + Bw - Bw^T, invert M = 2I - W in f64 (GJ,
// no pivot: sym part = 1.1I + A^TA is SPD), emit all streamed layouts.
// ---------------------------------------------------------------------------
__global__ __launch_bounds__(64) void k_prep(
    const float* __restrict__ W1, const float* __restrict__ Uw,
    const float* __restrict__ Aw, const float* __restrict__ Bw,
    const float* __restrict__ Pw, float* __restrict__ mats) {
  __shared__ double M[DD][2*DD];   // 64 KB exactly
  const int t = threadIdx.x;       // owns row t
  float* W1s   = mats + OFF_W1S;
  float* Uws   = mats + OFF_UWS;
  float* Winvs = mats + OFF_WINVS;
  float* Rms   = mats + OFF_RMS;
  float* Wss   = mats + OFF_WSS;
  float* Pws   = mats + OFF_PWS;

  for (int k = 0; k < DD; ++k) {
    double s = 0.0;
    for (int i = 0; i < DD; ++i)
      s += (double)Aw[i*DD+t] * (double)Aw[i*DD+k];
    double w = ((t==k) ? 0.9 : 0.0) - s + (double)Bw[t*DD+k] - (double)Bw[k*DD+t];
    Wss[k*DD+t] = (float)w;                    // W[t][k] at stream[k][t]
    M[t][k]    = ((t==k) ? 2.0 : 0.0) - w;     // M = 2I - W
    M[t][DD+k] = (t==k) ? 1.0 : 0.0;           // augmented identity
  }
  __syncthreads();
  for (int c = 0; c < DD; ++c) {
    if (t == c) {
      double p = 1.0 / M[c][c];
      for (int j = c; j < 2*DD; ++j) M[c][j] *= p;
    }
    __syncthreads();
    if (t != c) {
      double f = M[t][c];
      for (int j = c; j < 2*DD; ++j) M[t][j] -= f * M[c][j];
    }
    __syncthreads();
  }
  // M[t][DD+k] = Winv[t][k]
  for (int k = 0; k < INF; ++k) W1s[k*DD+t] = W1[t*INF+k];
  for (int k = 0; k < DD; ++k) {
    Uws[k*DD+t] = Uw[t*DD+k];
    float wi = (float)M[t][DD+k];
    Winvs[k*DD+t] = wi;
    Rms[k*DD+t]   = 2.0f*wi - ((k==t) ? 1.0f : 0.0f);
  }
  for (int o = 0; o < NOUT; ++o) Pws[t*NOUT+o] = Pw[o*DD+t];
}

// ---------------------------------------------------------------------------
// Phase B: bias = relu(x@W1^T + b1) @ Uw^T + Ub, stored TRANSPOSED [64][B]
// (coalesced writes + coalesced per-k reads in the solver).
// Thread-per-row; h staged in LDS SoA so the k-dynamic second GEMV never
// runtime-indexes a register array.
// ---------------------------------------------------------------------------
__global__ __launch_bounds__(256,2) void k_bias(
    const float* __restrict__ x, const float* __restrict__ b1,
    const float* __restrict__ Ub, const float* __restrict__ mats,
    float* __restrict__ biasT) {
  __shared__ float hls[DD*256];   // 64 KB, SoA [k][tid]
  const float* W1s = mats + OFF_W1S;
  const float* Uws = mats + OFF_UWS;
  const int tid = threadIdx.x;
  const long r = (long)blockIdx.x*256 + tid;
  const float* xr = x + r*INF;

  float h[DD];
  #pragma unroll
  for (int j = 0; j < DD; ++j) h[j] = b1[j];
  #pragma unroll 1
  for (int k4 = 0; k4 < INF/4; ++k4) {
    const float4 xv = *reinterpret_cast<const float4*>(xr + 4*k4);
    const float* mr = W1s + (4*k4)*DD;
    #pragma unroll
    for (int j = 0; j < DD; ++j) h[j] = fmaf(xv.x, mr[j], h[j]);
    #pragma unroll
    for (int j = 0; j < DD; ++j) h[j] = fmaf(xv.y, mr[DD+j], h[j]);
    #pragma unroll
    for (int j = 0; j < DD; ++j) h[j] = fmaf(xv.z, mr[2*DD+j], h[j]);
    #pragma unroll
    for (int j = 0; j < DD; ++j) h[j] = fmaf(xv.w, mr[3*DD+j], h[j]);
  }
  #pragma unroll
  for (int j = 0; j < DD; ++j) hls[j*256+tid] = fmaxf(h[j], 0.0f);

  float b[DD];
  #pragma unroll
  for (int j = 0; j < DD; ++j) b[j] = Ub[j];
  #pragma unroll 1
  for (int k = 0; k < DD; ++k) {
    const float hk = hls[k*256+tid];
    const float* mr = Uws + k*DD;
    #pragma unroll
    for (int j = 0; j < DD; ++j) b[j] = fmaf(hk, mr[j], b[j]);
  }
  #pragma unroll
  for (int j = 0; j < DD; ++j) biasT[(long)j*BROWS + r] = b[j];
}

// ---------------------------------------------------------------------------
// Phase C: c2 = 2*(bias @ Winv^T); 50 PR iterations via u <- c2 + |u| @ R
// (R = 2 Winv^T - I; iter 1 is analytically u1 = c2); then
// zn = relu(relu(u50) @ W^T + bias); out = zn @ Pw^T + Pb.
// |u| lives in LDS SoA (dynamic-k reads); u/c2 accumulators in VGPRs with
// static indexing only. Matrix rows are wave-uniform -> scalar loads.
// ---------------------------------------------------------------------------
__global__ __launch_bounds__(256,2) void k_solve(
    const float* __restrict__ biasT, const float* __restrict__ mats,
    const float* __restrict__ Pb, float* __restrict__ out) {
  __shared__ float tls[DD*256];   // 64 KB, SoA [k][tid]
  const float* Winvs = mats + OFF_WINVS;
  const float* Rms   = mats + OFF_RMS;
  const float* Wss   = mats + OFF_WSS;
  const float* Pws   = mats + OFF_PWS;
  const int tid = threadIdx.x;
  const long r = (long)blockIdx.x*256 + tid;

  // c2 = 2 * bias @ Winv^T
  float c2[DD];
  #pragma unroll
  for (int j = 0; j < DD; ++j) c2[j] = 0.0f;
  #pragma unroll 1
  for (int k = 0; k < DD; ++k) {
    const float bk = biasT[(long)k*BROWS + r];
    const float* mr = Winvs + k*DD;
    #pragma unroll
    for (int j = 0; j < DD; ++j) c2[j] = fmaf(bk, mr[j], c2[j]);
  }
  float u[DD];
  #pragma unroll
  for (int j = 0; j < DD; ++j) {
    c2[j] += c2[j];                       // c2 = 2c
    u[j] = c2[j];                         // u_1 = 2c  (iteration 1, since u12_1 = 0)
    tls[j*256+tid] = fabsf(c2[j]);        // |u_1|
  }

  #pragma unroll 1
  for (int it = 0; it < NITER-1; ++it) {
    #pragma unroll
    for (int j = 0; j < DD; ++j) u[j] = c2[j];
    #pragma unroll 2
    for (int k = 0; k < DD; ++k) {
      const float tk = tls[k*256+tid];
      const float* mr = Rms + k*DD;
      #pragma unroll
      for (int j = 0; j < DD; ++j) u[j] = fmaf(tk, mr[j], u[j]);
    }
    #pragma unroll
    for (int j = 0; j < DD; ++j) tls[j*256+tid] = fabsf(u[j]);
  }

  // z = relu(u50) -> LDS; zn = relu(z @ W^T + bias)
  #pragma unroll
  for (int j = 0; j < DD; ++j) tls[j*256+tid] = fmaxf(u[j], 0.0f);
  float zn[DD];
  #pragma unroll
  for (int j = 0; j < DD; ++j) zn[j] = biasT[(long)j*BROWS + r];
  #pragma unroll 1
  for (int k = 0; k < DD; ++k) {
    const float zk = tls[k*256+tid];
    const float* mr = Wss + k*DD;
    #pragma unroll
    for (int j = 0; j < DD; ++j) zn[j] = fmaf(zk, mr[j], zn[j]);
  }
  // out = relu(zn) @ Pw^T + Pb
  float o[NOUT];
  #pragma unroll
  for (int q = 0; q < NOUT; ++q) o[q] = Pb[q];
  #pragma unroll
  for (int j = 0; j < DD; ++j) {
    const float z2 = fmaxf(zn[j], 0.0f);
    const float* pr = Pws + j*NOUT;
    #pragma unroll
    for (int q = 0; q < NOUT; ++q) o[q] = fmaf(z2, pr[q], o[q]);
  }
  float4* op = reinterpret_cast<float4*>(out + r*NOUT);
  op[0] = make_float4(o[0], o[1], o[2], o[3]);
  op[1] = make_float4(o[4], o[5], o[6], o[7]);
}

extern "C" void kernel_launch(void* const* d_in, const int* in_sizes, int n_in,
                              void* d_out, int out_size, void* d_ws, size_t ws_size,
                              hipStream_t stream) {
  const float* x  = (const float*)d_in[0];
  const float* W1 = (const float*)d_in[1];
  const float* b1 = (const float*)d_in[2];
  const float* Uw = (const float*)d_in[3];
  const float* Ub = (const float*)d_in[4];
  const float* Aw = (const float*)d_in[5];
  const float* Bw = (const float*)d_in[6];
  const float* Pw = (const float*)d_in[7];
  const float* Pb = (const float*)d_in[8];
  float* outp  = (float*)d_out;
  float* biasT = (float*)d_ws;                       // [64][B] = 32 MB
  float* mats  = biasT + (size_t)DD*BROWS;           // ~100 KB of matrices

  k_prep <<<1, 64, 0, stream>>>(W1, Uw, Aw, Bw, Pw, mats);
  k_bias <<<BROWS/256, 256, 0, stream>>>(x, b1, Ub, mats, biasT);
  k_solve<<<BROWS/256, 256, 0, stream>>>(biasT, mats, Pb, outp);
}

// Round 2
// 772.951 us; speedup vs baseline: 1.9529x; 1.9529x over previous
//
#include <hip/hip_runtime.h>

#define BROWS 131072
#define DD 64
#define INF 128
#define NOUT 8
#define NITER 50

// mats layout (floats) inside ws, after biasT
#define OFF_W1S   0                  // [128][64]  W1s[k*64+j] = W1[j][k]
#define OFF_UWS   (8192)             // [64][64]   Uws[k*64+j] = Uw[j][k]
#define OFF_WINVS (8192+4096)        // [64][64]   Winvs[k*64+j] = Winv[j][k]
#define OFF_RMS   (8192+2*4096)      // [64][64]   Rms[k*64+j] = 2*Winv[j][k] - d(k,j)
#define OFF_WSS   (8192+3*4096)      // [64][64]   Wss[k*64+j] = W[j][k]
#define OFF_PWS   (8192+4*4096)      // [64][8]    Pws[j*8+o]  = Pw[o][j]

// ---------------------------------------------------------------------------
// Trivial streamed-layout transposes, fully parallel (was latency-bound in the
// old 1-wave prep). 12800 elements total.
// ---------------------------------------------------------------------------
__global__ __launch_bounds__(256) void k_layout(
    const float* __restrict__ W1, const float* __restrict__ Uw,
    const float* __restrict__ Pw, float* __restrict__ mats) {
  const int e = blockIdx.x * 256 + threadIdx.x;
  if (e < 8192) {                     // W1s[k*64+j] = W1[j*128+k]
    const int j = e & 63, k = e >> 6;
    mats[OFF_W1S + e] = W1[j * INF + k];
  } else if (e < 12288) {             // Uws[k*64+j] = Uw[j*64+k]
    const int e2 = e - 8192;
    const int j = e2 & 63, k = e2 >> 6;
    mats[OFF_UWS + e2] = Uw[j * DD + k];
  } else if (e < 12800) {             // Pws[j*8+o] = Pw[o*64+j]
    const int e2 = e - 12288;
    const int o = e2 & 7, j = e2 >> 3;
    mats[OFF_PWS + e2] = Pw[o * DD + j];
  }
}

// ---------------------------------------------------------------------------
// One-block prep: W = 0.9I - Aw^T Aw + Bw - Bw^T; invert M = 2I - W by f64
// Gauss-Jordan (sym part = 1.1I + A^T A is PD -> no pivoting needed).
// LDS holds the TRANSPOSED augmented matrix MT[j][t] = M[t][j] so the hot
// elimination accesses are lane-consecutive (free) or wave-broadcast.
// The same 64KB LDS is reused to stage Aw (f32) before MT is built.
// Thread mapping: t = tid&63 (owned row of M), kbase = (tid>>6)*16.
// ---------------------------------------------------------------------------
__global__ __launch_bounds__(256) void k_inv(
    const float* __restrict__ Aw, const float* __restrict__ Bw,
    float* __restrict__ mats) {
  __shared__ double MT[2 * DD][DD];          // 64 KB: MT[j][t] = M[t][j] (augmented)
  float* As = reinterpret_cast<float*>(&MT[0][0]);   // phase-A staging of Aw
  float* Winvs = mats + OFF_WINVS;
  float* Rms   = mats + OFF_RMS;
  float* Wss   = mats + OFF_WSS;
  const int tid = threadIdx.x;
  const int t = tid & 63;                    // owned row of M
  const int cg = tid >> 6;                   // 0..3
  const int kbase = cg * 16;

  // phase A: stage Aw (4096 f32) into LDS, coalesced
  #pragma unroll
  for (int q = 0; q < 16; ++q) As[q * 256 + tid] = Aw[q * 256 + tid];
  __syncthreads();

  // phase B: S[t][k] = sum_i A[i][t]*A[i][k] for k = kbase..kbase+15 (f64 acc)
  double s[16];
  #pragma unroll
  for (int q = 0; q < 16; ++q) s[q] = 0.0;
  for (int i = 0; i < DD; ++i) {
    const double at = (double)As[i * DD + t];          // lane-consecutive
    const float* ak = As + i * DD + kbase;             // wave-broadcast
    #pragma unroll
    for (int q = 0; q < 16; ++q) s[q] += at * (double)ak[q];
  }
  double wreg[16];
  #pragma unroll
  for (int q = 0; q < 16; ++q) {
    const int k = kbase + q;
    const double w = ((t == k) ? 0.9 : 0.0) - s[q]
                   + (double)Bw[t * DD + k] - (double)Bw[k * DD + t];
    wreg[q] = w;
    Wss[k * DD + t] = (float)w;             // W[t][k] at stream slot [k][t]
  }
  __syncthreads();                          // done reading As; MT may overwrite

  // phase C: build augmented MT
  #pragma unroll
  for (int q = 0; q < 16; ++q) {
    const int k = kbase + q;
    MT[k][t]      = ((t == k) ? 2.0 : 0.0) - wreg[q];  // M = 2I - W
    MT[DD + k][t] = (t == k) ? 1.0 : 0.0;              // augmented identity
  }
  __syncthreads();

  // phase D: Gauss-Jordan, 64 pivots, 3 barriers each
  for (int c = 0; c < DD; ++c) {
    const double p = 1.0 / MT[c][c];                   // broadcast read
    const double f = (t == c) ? 0.0 : MT[c][t];        // M[t][c], lane-consecutive
    __syncthreads();
    if (tid < 2 * DD) MT[tid][c] *= p;                 // scale pivot row of M
    __syncthreads();
    if (t != c) {                                      // eliminate (row c untouched)
      #pragma unroll 4
      for (int jj = 0; jj < 32; ++jj) {
        const int j = cg * 32 + jj;
        MT[j][t] -= f * MT[j][c];                      // bcast MT[j][c], consec MT[j][t]
      }
    }
    __syncthreads();
  }

  // phase E: Winv[t][k] = MT[64+k][t]; emit streamed Winv^T and R = 2Winv^T - I
  #pragma unroll
  for (int q = 0; q < 16; ++q) {
    const int k = kbase + q;
    const float wi = (float)MT[DD + k][t];
    Winvs[k * DD + t] = wi;
    Rms[k * DD + t]   = 2.0f * wi - ((k == t) ? 1.0f : 0.0f);
  }
}

// ---------------------------------------------------------------------------
// Phase B: bias = relu(x@W1^T + b1) @ Uw^T + Ub, stored TRANSPOSED [64][B].
// ---------------------------------------------------------------------------
__global__ __launch_bounds__(256,2) void k_bias(
    const float* __restrict__ x, const float* __restrict__ b1,
    const float* __restrict__ Ub, const float* __restrict__ mats,
    float* __restrict__ biasT) {
  __shared__ float hls[DD*256];   // 64 KB, SoA [k][tid]
  const float* W1s = mats + OFF_W1S;
  const float* Uws = mats + OFF_UWS;
  const int tid = threadIdx.x;
  const long r = (long)blockIdx.x*256 + tid;
  const float* xr = x + r*INF;

  float h[DD];
  #pragma unroll
  for (int j = 0; j < DD; ++j) h[j] = b1[j];
  #pragma unroll 1
  for (int k4 = 0; k4 < INF/4; ++k4) {
    const float4 xv = *reinterpret_cast<const float4*>(xr + 4*k4);
    const float* mr = W1s + (4*k4)*DD;
    #pragma unroll
    for (int j = 0; j < DD; ++j) h[j] = fmaf(xv.x, mr[j], h[j]);
    #pragma unroll
    for (int j = 0; j < DD; ++j) h[j] = fmaf(xv.y, mr[DD+j], h[j]);
    #pragma unroll
    for (int j = 0; j < DD; ++j) h[j] = fmaf(xv.z, mr[2*DD+j], h[j]);
    #pragma unroll
    for (int j = 0; j < DD; ++j) h[j] = fmaf(xv.w, mr[3*DD+j], h[j]);
  }
  #pragma unroll
  for (int j = 0; j < DD; ++j) hls[j*256+tid] = fmaxf(h[j], 0.0f);

  float b[DD];
  #pragma unroll
  for (int j = 0; j < DD; ++j) b[j] = Ub[j];
  #pragma unroll 1
  for (int k = 0; k < DD; ++k) {
    const float hk = hls[k*256+tid];
    const float* mr = Uws + k*DD;
    #pragma unroll
    for (int j = 0; j < DD; ++j) b[j] = fmaf(hk, mr[j], b[j]);
  }
  #pragma unroll
  for (int j = 0; j < DD; ++j) biasT[(long)j*BROWS + r] = b[j];
}

// ---------------------------------------------------------------------------
// Phase C: c2 = 2*(bias @ Winv^T); 50 PR iterations via u <- c2 + |u| @ R;
// then zn = relu(relu(u50) @ W^T + bias); out = zn @ Pw^T + Pb.
// ---------------------------------------------------------------------------
__global__ __launch_bounds__(256,2) void k_solve(
    const float* __restrict__ biasT, const float* __restrict__ mats,
    const float* __restrict__ Pb, float* __restrict__ out) {
  __shared__ float tls[DD*256];   // 64 KB, SoA [k][tid]
  const float* Winvs = mats + OFF_WINVS;
  const float* Rms   = mats + OFF_RMS;
  const float* Wss   = mats + OFF_WSS;
  const float* Pws   = mats + OFF_PWS;
  const int tid = threadIdx.x;
  const long r = (long)blockIdx.x*256 + tid;

  // c2 = 2 * bias @ Winv^T
  float c2[DD];
  #pragma unroll
  for (int j = 0; j < DD; ++j) c2[j] = 0.0f;
  #pragma unroll 1
  for (int k = 0; k < DD; ++k) {
    const float bk = biasT[(long)k*BROWS + r];
    const float* mr = Winvs + k*DD;
    #pragma unroll
    for (int j = 0; j < DD; ++j) c2[j] = fmaf(bk, mr[j], c2[j]);
  }
  float u[DD];
  #pragma unroll
  for (int j = 0; j < DD; ++j) {
    c2[j] += c2[j];                       // c2 = 2c
    u[j] = c2[j];                         // u_1 = 2c
    tls[j*256+tid] = fabsf(c2[j]);        // |u_1|
  }

  #pragma unroll 1
  for (int it = 0; it < NITER-1; ++it) {
    #pragma unroll
    for (int j = 0; j < DD; ++j) u[j] = c2[j];
    #pragma unroll 2
    for (int k = 0; k < DD; ++k) {
      const float tk = tls[k*256+tid];
      const float* mr = Rms + k*DD;
      #pragma unroll
      for (int j = 0; j < DD; ++j) u[j] = fmaf(tk, mr[j], u[j]);
    }
    #pragma unroll
    for (int j = 0; j < DD; ++j) tls[j*256+tid] = fabsf(u[j]);
  }

  // z = relu(u50) -> LDS; zn = relu(z @ W^T + bias)
  #pragma unroll
  for (int j = 0; j < DD; ++j) tls[j*256+tid] = fmaxf(u[j], 0.0f);
  float zn[DD];
  #pragma unroll
  for (int j = 0; j < DD; ++j) zn[j] = biasT[(long)j*BROWS + r];
  #pragma unroll 1
  for (int k = 0; k < DD; ++k) {
    const float zk = tls[k*256+tid];
    const float* mr = Wss + k*DD;
    #pragma unroll
    for (int j = 0; j < DD; ++j) zn[j] = fmaf(zk, mr[j], zn[j]);
  }
  // out = relu(zn) @ Pw^T + Pb
  float o[NOUT];
  #pragma unroll
  for (int q = 0; q < NOUT; ++q) o[q] = Pb[q];
  #pragma unroll
  for (int j = 0; j < DD; ++j) {
    const float z2 = fmaxf(zn[j], 0.0f);
    const float* pr = Pws + j*NOUT;
    #pragma unroll
    for (int q = 0; q < NOUT; ++q) o[q] = fmaf(z2, pr[q], o[q]);
  }
  float4* op = reinterpret_cast<float4*>(out + r*NOUT);
  op[0] = make_float4(o[0], o[1], o[2], o[3]);
  op[1] = make_float4(o[4], o[5], o[6], o[7]);
}

extern "C" void kernel_launch(void* const* d_in, const int* in_sizes, int n_in,
                              void* d_out, int out_size, void* d_ws, size_t ws_size,
                              hipStream_t stream) {
  const float* x  = (const float*)d_in[0];
  const float* W1 = (const float*)d_in[1];
  const float* b1 = (const float*)d_in[2];
  const float* Uw = (const float*)d_in[3];
  const float* Ub = (const float*)d_in[4];
  const float* Aw = (const float*)d_in[5];
  const float* Bw = (const float*)d_in[6];
  const float* Pw = (const float*)d_in[7];
  const float* Pb = (const float*)d_in[8];
  float* outp  = (float*)d_out;
  float* biasT = (float*)d_ws;                       // [64][B] = 32 MB
  float* mats  = biasT + (size_t)DD*BROWS;           // ~100 KB of matrices

  k_layout<<<50, 256, 0, stream>>>(W1, Uw, Pw, mats);
  k_inv   <<<1, 256, 0, stream>>>(Aw, Bw, mats);
  k_bias  <<<BROWS/256, 256, 0, stream>>>(x, b1, Ub, mats, biasT);
  k_solve <<<BROWS/256, 256, 0, stream>>>(biasT, mats, Pb, outp);
}

// Round 5
// 340.163 us; speedup vs baseline: 4.4376x; 2.2723x over previous
//
#include <hip/hip_runtime.h>

#define BROWS 131072
#define DD 64
#define INF 128
#define NOUT 8
#define NITER 50

// mats layout (floats) inside ws, after biasT — unchanged
#define OFF_W1S   0                  // [128][64]  W1s[k*64+j] = W1[j][k]
#define OFF_UWS   (8192)             // [64][64]   Uws[k*64+j] = Uw[j][k]
#define OFF_WINVS (8192+4096)        // [64][64]   Winvs[k*64+j] = Winv[j][k]
#define OFF_RMS   (8192+2*4096)      // [64][64]   Rms[k*64+j] = R^T[j][k]
#define OFF_WSS   (8192+3*4096)      // [64][64]   Wss[k*64+j] = W[j][k]
#define OFF_PWS   (8192+4*4096)      // [64][8]    Pws[j*8+o]  = Pw[o][j]

typedef __attribute__((ext_vector_type(8))) short bf16x8;  // 4 VGPR A/B frag
typedef __attribute__((ext_vector_type(4))) float f32x4;   // 16x16 C/D frag

union FragU { uint4 u; bf16x8 f; };

// pack two f32 into one dword of 2 bf16 (bit-truncation; first arg -> low16)
__device__ __forceinline__ unsigned pk2(float a, float b) {
  return (__float_as_uint(a) >> 16) | (__float_as_uint(b) & 0xFFFF0000u);
}
// exact residual v - bf16trunc(v)
__device__ __forceinline__ float res_lo(float v) {
  return v - __uint_as_float(__float_as_uint(v) & 0xFFFF0000u);
}
__device__ __forceinline__ bf16x8 frag4(unsigned a, unsigned b, unsigned c, unsigned d) {
  FragU t; t.u.x = a; t.u.y = b; t.u.z = c; t.u.w = d; return t.f;
}
__device__ __forceinline__ f32x4 MF16(bf16x8 a, bf16x8 b, f32x4 c) {
  return __builtin_amdgcn_mfma_f32_16x16x32_bf16(a, b, c, 0, 0, 0);
}

// A-fragment (hi,lo planes) from streamed f32 matrix src[k*DD+j] = Mat[j][k].
// m97-verified map: lane holds row j = 16*rt + (lane&15), k = kb + s,
// kb = 32*ki + 8*(lane>>4), slots s = 0..7 consecutive.
__device__ __forceinline__ void build_a16(const float* __restrict__ src,
    int j, int kb, float scale, bf16x8& fh, bf16x8& fl) {
  unsigned wh[4], wl[4];
  #pragma unroll
  for (int p = 0; p < 4; ++p) {
    const float v0 = src[(kb + 2*p    ) * DD + j] * scale;
    const float v1 = src[(kb + 2*p + 1) * DD + j] * scale;
    wh[p] = pk2(v0, v1);
    wl[p] = pk2(res_lo(v0), res_lo(v1));
  }
  fh = frag4(wh[0], wh[1], wh[2], wh[3]);
  fl = frag4(wl[0], wl[1], wl[2], wl[3]);
}

// B-fragment (hi,lo) from 8 explicit f32 row values, same slot map as build_a16.
__device__ __forceinline__ void build_b8(const float* v, bf16x8& fh, bf16x8& fl) {
  fh = frag4(pk2(v[0],v[1]), pk2(v[2],v[3]), pk2(v[4],v[5]), pk2(v[6],v[7]));
  fl = frag4(pk2(res_lo(v[0]),res_lo(v[1])), pk2(res_lo(v[2]),res_lo(v[3])),
             pk2(res_lo(v[4]),res_lo(v[5])), pk2(res_lo(v[6]),res_lo(v[7])));
}

// Store one C/D tile into the packed-bf16 LDS state column.
// C/D map (m89-verified): reg r -> row 16*rt + 4*kg + r, col = lane&15.
// Column layout (u32 words): hi plane words 0..31 (word w = rows 2w,2w+1),
// lo plane words 32..63. MODE: 1 = abs, 2 = relu.
template<int MODE>
__device__ __forceinline__ void store_pk(unsigned* stc, int kg, int rt, f32x4 a) {
  float x0 = a[0], x1 = a[1], x2 = a[2], x3 = a[3];
  if (MODE == 1) { x0=fabsf(x0); x1=fabsf(x1); x2=fabsf(x2); x3=fabsf(x3); }
  if (MODE == 2) { x0=fmaxf(x0,0.f); x1=fmaxf(x1,0.f); x2=fmaxf(x2,0.f); x3=fmaxf(x3,0.f); }
  uint2 h, l;
  h.x = pk2(x0, x1);                    h.y = pk2(x2, x3);
  l.x = pk2(res_lo(x0), res_lo(x1));    l.y = pk2(res_lo(x2), res_lo(x3));
  *reinterpret_cast<uint2*>(stc + 8*rt + 2*kg)      = h;
  *reinterpret_cast<uint2*>(stc + 32 + 8*rt + 2*kg) = l;
}

// ---------------------------------------------------------------------------
// k_layout / k_inv / k_bias: unchanged (verified in round 2).
// ---------------------------------------------------------------------------
__global__ __launch_bounds__(256) void k_layout(
    const float* __restrict__ W1, const float* __restrict__ Uw,
    const float* __restrict__ Pw, float* __restrict__ mats) {
  const int e = blockIdx.x * 256 + threadIdx.x;
  if (e < 8192) {
    const int j = e & 63, k = e >> 6;
    mats[OFF_W1S + e] = W1[j * INF + k];
  } else if (e < 12288) {
    const int e2 = e - 8192;
    const int j = e2 & 63, k = e2 >> 6;
    mats[OFF_UWS + e2] = Uw[j * DD + k];
  } else if (e < 12800) {
    const int e2 = e - 12288;
    const int o = e2 & 7, j = e2 >> 3;
    mats[OFF_PWS + e2] = Pw[o * DD + j];
  }
}

__global__ __launch_bounds__(256) void k_inv(
    const float* __restrict__ Aw, const float* __restrict__ Bw,
    float* __restrict__ mats) {
  __shared__ double MT[2 * DD][DD];
  float* As = reinterpret_cast<float*>(&MT[0][0]);
  float* Winvs = mats + OFF_WINVS;
  float* Rms   = mats + OFF_RMS;
  float* Wss   = mats + OFF_WSS;
  const int tid = threadIdx.x;
  const int t = tid & 63;
  const int cg = tid >> 6;
  const int kbase = cg * 16;

  #pragma unroll
  for (int q = 0; q < 16; ++q) As[q * 256 + tid] = Aw[q * 256 + tid];
  __syncthreads();

  double s[16];
  #pragma unroll
  for (int q = 0; q < 16; ++q) s[q] = 0.0;
  for (int i = 0; i < DD; ++i) {
    const double at = (double)As[i * DD + t];
    const float* ak = As + i * DD + kbase;
    #pragma unroll
    for (int q = 0; q < 16; ++q) s[q] += at * (double)ak[q];
  }
  double wreg[16];
  #pragma unroll
  for (int q = 0; q < 16; ++q) {
    const int k = kbase + q;
    const double w = ((t == k) ? 0.9 : 0.0) - s[q]
                   + (double)Bw[t * DD + k] - (double)Bw[k * DD + t];
    wreg[q] = w;
    Wss[k * DD + t] = (float)w;
  }
  __syncthreads();

  #pragma unroll
  for (int q = 0; q < 16; ++q) {
    const int k = kbase + q;
    MT[k][t]      = ((t == k) ? 2.0 : 0.0) - wreg[q];
    MT[DD + k][t] = (t == k) ? 1.0 : 0.0;
  }
  __syncthreads();

  for (int c = 0; c < DD; ++c) {
    const double p = 1.0 / MT[c][c];
    const double f = (t == c) ? 0.0 : MT[c][t];
    __syncthreads();
    if (tid < 2 * DD) MT[tid][c] *= p;
    __syncthreads();
    if (t != c) {
      #pragma unroll 4
      for (int jj = 0; jj < 32; ++jj) {
        const int j = cg * 32 + jj;
        MT[j][t] -= f * MT[j][c];
      }
    }
    __syncthreads();
  }

  #pragma unroll
  for (int q = 0; q < 16; ++q) {
    const int k = kbase + q;
    const float wi = (float)MT[DD + k][t];
    Winvs[k * DD + t] = wi;
    Rms[k * DD + t]   = 2.0f * wi - ((k == t) ? 1.0f : 0.0f);
  }
}

__global__ __launch_bounds__(256,2) void k_bias(
    const float* __restrict__ x, const float* __restrict__ b1,
    const float* __restrict__ Ub, const float* __restrict__ mats,
    float* __restrict__ biasT) {
  __shared__ float hls[DD*256];
  const float* W1s = mats + OFF_W1S;
  const float* Uws = mats + OFF_UWS;
  const int tid = threadIdx.x;
  const long r = (long)blockIdx.x*256 + tid;
  const float* xr = x + r*INF;

  float h[DD];
  #pragma unroll
  for (int j = 0; j < DD; ++j) h[j] = b1[j];
  #pragma unroll 1
  for (int k4 = 0; k4 < INF/4; ++k4) {
    const float4 xv = *reinterpret_cast<const float4*>(xr + 4*k4);
    const float* mr = W1s + (4*k4)*DD;
    #pragma unroll
    for (int j = 0; j < DD; ++j) h[j] = fmaf(xv.x, mr[j], h[j]);
    #pragma unroll
    for (int j = 0; j < DD; ++j) h[j] = fmaf(xv.y, mr[DD+j], h[j]);
    #pragma unroll
    for (int j = 0; j < DD; ++j) h[j] = fmaf(xv.z, mr[2*DD+j], h[j]);
    #pragma unroll
    for (int j = 0; j < DD; ++j) h[j] = fmaf(xv.w, mr[3*DD+j], h[j]);
  }
  #pragma unroll
  for (int j = 0; j < DD; ++j) hls[j*256+tid] = fmaxf(h[j], 0.0f);

  float b[DD];
  #pragma unroll
  for (int j = 0; j < DD; ++j) b[j] = Ub[j];
  #pragma unroll 1
  for (int k = 0; k < DD; ++k) {
    const float hk = hls[k*256+tid];
    const float* mr = Uws + k*DD;
    #pragma unroll
    for (int j = 0; j < DD; ++j) b[j] = fmaf(hk, mr[j], b[j]);
  }
  #pragma unroll
  for (int j = 0; j < DD; ++j) biasT[(long)j*BROWS + r] = b[j];
}

// ---------------------------------------------------------------------------
// Phase C (MFMA 16x16x32, m97-verified premise set): per wave 64 dims x 16
// batch cols. State kept in LDS pre-packed as bf16 hi/lo planes.
// ---------------------------------------------------------------------------
__global__ __launch_bounds__(256) void k_solve(
    const float* __restrict__ biasT, const float* __restrict__ mats,
    const float* __restrict__ Pb, float* __restrict__ out) {
  __shared__ unsigned stp[64 * 68];   // packed state: [col][68 words]
  __shared__ float zls[64 * 66];      // epilogue z staging
  const float* Winvs = mats + OFF_WINVS;
  const float* Rms   = mats + OFF_RMS;
  const float* Wss   = mats + OFF_WSS;
  const float* Pws   = mats + OFF_PWS;
  const int tid  = threadIdx.x;
  const int lane = tid & 63, wv = tid >> 6;
  const int l15  = lane & 15, kg = lane >> 4;     // col-in-tile, k/row group
  const int ccol = wv * 16 + l15;                 // block-local batch col
  const size_t ncol = (size_t)blockIdx.x * 64 + ccol;
  unsigned* stc = stp + ccol * 68;

  // R^T fragments resident in registers
  bf16x8 rFh[4][2], rFl[4][2];
  #pragma unroll
  for (int rt = 0; rt < 4; ++rt)
    #pragma unroll
    for (int ki = 0; ki < 2; ++ki)
      build_a16(Rms, 16*rt + l15, 32*ki + 8*kg, 1.0f, rFh[rt][ki], rFl[rt][ki]);

  // ---- c2 = 2 * Winv @ bias^T (B filled from global biasT, same slot map)
  f32x4 c2a[4];
  #pragma unroll
  for (int rt = 0; rt < 4; ++rt) c2a[rt] = (f32x4){0.f, 0.f, 0.f, 0.f};
  #pragma unroll
  for (int ki = 0; ki < 2; ++ki) {
    float bv[8];
    const float* bp = biasT + (size_t)(32*ki + 8*kg) * BROWS + ncol;
    #pragma unroll
    for (int s = 0; s < 8; ++s) bv[s] = bp[(size_t)s * BROWS];
    bf16x8 Bh, Bl; build_b8(bv, Bh, Bl);
    #pragma unroll
    for (int rt = 0; rt < 4; ++rt) {
      bf16x8 ah, al;
      build_a16(Winvs, 16*rt + l15, 32*ki + 8*kg, 2.0f, ah, al);
      c2a[rt] = MF16(ah, Bh, c2a[rt]);
      c2a[rt] = MF16(ah, Bl, c2a[rt]);
      c2a[rt] = MF16(al, Bh, c2a[rt]);
    }
  }
  // state = |u1| = |c2|
  #pragma unroll
  for (int rt = 0; rt < 4; ++rt) store_pk<1>(stc, kg, rt, c2a[rt]);

  // ---- u_{k+1} = c2 + R^T|u_k| : 48 abs iterations, then 1 relu
  f32x4 u[4];
  #pragma unroll 1
  for (int it = 0; it < NITER - 2; ++it) {
    #pragma unroll
    for (int ki = 0; ki < 2; ++ki) {
      FragU bh, bl;
      bh.u = *reinterpret_cast<const uint4*>(stc + 16*ki + 4*kg);
      bl.u = *reinterpret_cast<const uint4*>(stc + 32 + 16*ki + 4*kg);
      #pragma unroll
      for (int rt = 0; rt < 4; ++rt) {
        f32x4 base = (ki == 0) ? c2a[rt] : u[rt];
        u[rt] = MF16(rFh[rt][ki], bh.f, base);
        u[rt] = MF16(rFh[rt][ki], bl.f, u[rt]);
        u[rt] = MF16(rFl[rt][ki], bh.f, u[rt]);
      }
    }
    #pragma unroll
    for (int rt = 0; rt < 4; ++rt) store_pk<1>(stc, kg, rt, u[rt]);
  }
  // final PR step -> u50; state = relu(u50)
  #pragma unroll
  for (int ki = 0; ki < 2; ++ki) {
    FragU bh, bl;
    bh.u = *reinterpret_cast<const uint4*>(stc + 16*ki + 4*kg);
    bl.u = *reinterpret_cast<const uint4*>(stc + 32 + 16*ki + 4*kg);
    #pragma unroll
    for (int rt = 0; rt < 4; ++rt) {
      f32x4 base = (ki == 0) ? c2a[rt] : u[rt];
      u[rt] = MF16(rFh[rt][ki], bh.f, base);
      u[rt] = MF16(rFh[rt][ki], bl.f, u[rt]);
      u[rt] = MF16(rFl[rt][ki], bh.f, u[rt]);
    }
  }
  #pragma unroll
  for (int rt = 0; rt < 4; ++rt) store_pk<2>(stc, kg, rt, u[rt]);

  // ---- zn = relu(W @ z + bias) with bias C-init via verified C/D map
  f32x4 zn[4];
  #pragma unroll
  for (int rt = 0; rt < 4; ++rt)
    #pragma unroll
    for (int r = 0; r < 4; ++r)
      zn[rt][r] = biasT[(size_t)(16*rt + 4*kg + r) * BROWS + ncol];
  #pragma unroll
  for (int ki = 0; ki < 2; ++ki) {
    FragU bh, bl;
    bh.u = *reinterpret_cast<const uint4*>(stc + 16*ki + 4*kg);
    bl.u = *reinterpret_cast<const uint4*>(stc + 32 + 16*ki + 4*kg);
    #pragma unroll
    for (int rt = 0; rt < 4; ++rt) {
      bf16x8 wh_, wl_;
      build_a16(Wss, 16*rt + l15, 32*ki + 8*kg, 1.0f, wh_, wl_);
      zn[rt] = MF16(wh_, bh.f, zn[rt]);
      zn[rt] = MF16(wh_, bl.f, zn[rt]);
      zn[rt] = MF16(wl_, bh.f, zn[rt]);
    }
  }

  __syncthreads();   // all waves done reading state before zls overwrites LDS? (separate arrays; barrier orders the block anyway)
  #pragma unroll
  for (int rt = 0; rt < 4; ++rt)
    #pragma unroll
    for (int r = 0; r < 4; ++r)
      zls[(16*rt + 4*kg + r) * 66 + ccol] = fmaxf(zn[rt][r], 0.f);
  __syncthreads();

  // ---- out = zn @ Pw^T + Pb
  if (tid < 64) {
    float o[NOUT];
    #pragma unroll
    for (int q = 0; q < NOUT; ++q) o[q] = Pb[q];
    #pragma unroll
    for (int j = 0; j < DD; ++j) {
      const float z = zls[j * 66 + tid];
      const float* pr = Pws + j * NOUT;
      #pragma unroll
      for (int q = 0; q < NOUT; ++q) o[q] = fmaf(z, pr[q], o[q]);
    }
    float4* op = reinterpret_cast<float4*>(out + ((size_t)blockIdx.x * 64 + tid) * NOUT);
    op[0] = make_float4(o[0], o[1], o[2], o[3]);
    op[1] = make_float4(o[4], o[5], o[6], o[7]);
  }
}

extern "C" void kernel_launch(void* const* d_in, const int* in_sizes, int n_in,
                              void* d_out, int out_size, void* d_ws, size_t ws_size,
                              hipStream_t stream) {
  const float* x  = (const float*)d_in[0];
  const float* W1 = (const float*)d_in[1];
  const float* b1 = (const float*)d_in[2];
  const float* Uw = (const float*)d_in[3];
  const float* Ub = (const float*)d_in[4];
  const float* Aw = (const float*)d_in[5];
  const float* Bw = (const float*)d_in[6];
  const float* Pw = (const float*)d_in[7];
  const float* Pb = (const float*)d_in[8];
  float* outp  = (float*)d_out;
  float* biasT = (float*)d_ws;                       // [64][B] = 32 MB
  float* mats  = biasT + (size_t)DD*BROWS;           // ~100 KB of matrices

  k_layout<<<50, 256, 0, stream>>>(W1, Uw, Pw, mats);
  k_inv   <<<1, 256, 0, stream>>>(Aw, Bw, mats);
  k_bias  <<<BROWS/256, 256, 0, stream>>>(x, b1, Ub, mats, biasT);
  k_solve <<<BROWS/64, 256, 0, stream>>>(biasT, mats, Pb, outp);
}

// Round 6
// 272.875 us; speedup vs baseline: 5.5318x; 1.2466x over previous
//
#include <hip/hip_runtime.h>

#define BROWS 131072
#define DD 64
#define INF 128
#define NOUT 8
#define NITER 50
#define STW 76   // state column stride in words; 76/4=19≡3 (mod 8) → uniform bank spread

// mats layout (floats) in ws
#define OFF_W1S   0        // [128][64]  W1s[k*64+j] = W1[j][k]
#define OFF_UWS   8192     // [64][64]   Uws[k*64+j] = Uw[j][k]
#define OFF_WINVS 12288    // [64][64]   Winvs[k*64+j] = Winv[j][k]
#define OFF_RMS   16384    // [64][64]   Rms[k*64+j] = R^T[j][k]
#define OFF_WSS   20480    // [64][64]   Wss[k*64+j] = W[j][k]
#define OFF_PWS   24576    // [64][16]   PwsA[j*16+o] = (o<8) ? Pw[o][j] : 0

typedef __attribute__((ext_vector_type(8))) short bf16x8;  // 4 VGPR A/B frag
typedef __attribute__((ext_vector_type(4))) float f32x4;   // 16x16 C/D frag

union FragU { uint4 u; bf16x8 f; };

// pack two f32 into one dword of 2 bf16 (bit-truncation; first arg -> low16)
__device__ __forceinline__ unsigned pk2(float a, float b) {
  return (__float_as_uint(a) >> 16) | (__float_as_uint(b) & 0xFFFF0000u);
}
// exact residual v - bf16trunc(v)
__device__ __forceinline__ float res_lo(float v) {
  return v - __uint_as_float(__float_as_uint(v) & 0xFFFF0000u);
}
__device__ __forceinline__ bf16x8 frag4(unsigned a, unsigned b, unsigned c, unsigned d) {
  FragU t; t.u.x = a; t.u.y = b; t.u.z = c; t.u.w = d; return t.f;
}
__device__ __forceinline__ f32x4 MF16(bf16x8 a, bf16x8 b, f32x4 c) {
  return __builtin_amdgcn_mfma_f32_16x16x32_bf16(a, b, c, 0, 0, 0);
}

// A-fragment (hi,lo planes) from streamed f32 matrix src[k*stride + j] = Mat[j][k].
// Verified map: lane holds row j, slots s=0..7 are k = kb..kb+7, kb = 32*ki+8*(lane>>4).
__device__ __forceinline__ void build_a16(const float* __restrict__ src, int stride,
    int j, int kb, float scale, bf16x8& fh, bf16x8& fl) {
  unsigned wh[4], wl[4];
  #pragma unroll
  for (int p = 0; p < 4; ++p) {
    const float v0 = src[(kb + 2*p    ) * stride + j] * scale;
    const float v1 = src[(kb + 2*p + 1) * stride + j] * scale;
    wh[p] = pk2(v0, v1);
    wl[p] = pk2(res_lo(v0), res_lo(v1));
  }
  fh = frag4(wh[0], wh[1], wh[2], wh[3]);
  fl = frag4(wl[0], wl[1], wl[2], wl[3]);
}

// B-fragment (hi,lo) from 8 explicit f32 values, same slot map as build_a16.
__device__ __forceinline__ void build_b8(const float* v, bf16x8& fh, bf16x8& fl) {
  fh = frag4(pk2(v[0],v[1]), pk2(v[2],v[3]), pk2(v[4],v[5]), pk2(v[6],v[7]));
  fl = frag4(pk2(res_lo(v[0]),res_lo(v[1])), pk2(res_lo(v[2]),res_lo(v[3])),
             pk2(res_lo(v[4]),res_lo(v[5])), pk2(res_lo(v[6]),res_lo(v[7])));
}

// Store one C/D tile into the packed-bf16 LDS state column.
// C/D map (verified): reg r -> row 16*rt + 4*kg + r, col = lane&15.
// Column words: hi plane 0..31 (word w = rows 2w,2w+1), lo plane 32..63.
// MODE: 0 = raw, 1 = abs, 2 = relu.
template<int MODE>
__device__ __forceinline__ void store_pk(unsigned* stc, int kg, int rt, f32x4 a) {
  float x0 = a[0], x1 = a[1], x2 = a[2], x3 = a[3];
  if (MODE == 1) { x0=fabsf(x0); x1=fabsf(x1); x2=fabsf(x2); x3=fabsf(x3); }
  if (MODE == 2) { x0=fmaxf(x0,0.f); x1=fmaxf(x1,0.f); x2=fmaxf(x2,0.f); x3=fmaxf(x3,0.f); }
  uint2 h, l;
  h.x = pk2(x0, x1);                    h.y = pk2(x2, x3);
  l.x = pk2(res_lo(x0), res_lo(x1));    l.y = pk2(res_lo(x2), res_lo(x3));
  *reinterpret_cast<uint2*>(stc + 8*rt + 2*kg)      = h;
  *reinterpret_cast<uint2*>(stc + 32 + 8*rt + 2*kg) = l;
}

// acc[rt] += scale(A) @ state   (A streamed f32 64x64, B = packed LDS state)
__device__ __forceinline__ void product3(f32x4* acc, const float* __restrict__ Asrc,
    float scale, const unsigned* stc, int kg, int l15) {
  #pragma unroll
  for (int ki = 0; ki < 2; ++ki) {
    FragU bh, bl;
    bh.u = *reinterpret_cast<const uint4*>(stc + 16*ki + 4*kg);
    bl.u = *reinterpret_cast<const uint4*>(stc + 32 + 16*ki + 4*kg);
    #pragma unroll
    for (int rt = 0; rt < 4; ++rt) {
      bf16x8 ah, al;
      build_a16(Asrc, DD, 16*rt + l15, 32*ki + 8*kg, scale, ah, al);
      acc[rt] = MF16(ah, bh.f, acc[rt]);
      acc[rt] = MF16(ah, bl.f, acc[rt]);
      acc[rt] = MF16(al, bh.f, acc[rt]);
    }
  }
}

// ---------------------------------------------------------------------------
// Streamed-layout transposes (W1s, Uws, PwsA).
// ---------------------------------------------------------------------------
__global__ __launch_bounds__(256) void k_layout(
    const float* __restrict__ W1, const float* __restrict__ Uw,
    const float* __restrict__ Pw, float* __restrict__ mats) {
  const int e = blockIdx.x * 256 + threadIdx.x;
  if (e < 8192) {
    const int j = e & 63, k = e >> 6;
    mats[OFF_W1S + e] = W1[j * INF + k];
  } else if (e < 12288) {
    const int e2 = e - 8192;
    const int j = e2 & 63, k = e2 >> 6;
    mats[OFF_UWS + e2] = Uw[j * DD + k];
  } else if (e < 13312) {
    const int e2 = e - 12288;
    const int o = e2 & 15, j = e2 >> 4;
    mats[OFF_PWS + e2] = (o < NOUT) ? Pw[o * DD + j] : 0.0f;
  }
}

// ---------------------------------------------------------------------------
// One-block prep (verified): f64 Gauss-Jordan inversion of M = 2I - W.
// ---------------------------------------------------------------------------
__global__ __launch_bounds__(256) void k_inv(
    const float* __restrict__ Aw, const float* __restrict__ Bw,
    float* __restrict__ mats) {
  __shared__ double MT[2 * DD][DD];
  float* As = reinterpret_cast<float*>(&MT[0][0]);
  float* Winvs = mats + OFF_WINVS;
  float* Rms   = mats + OFF_RMS;
  float* Wss   = mats + OFF_WSS;
  const int tid = threadIdx.x;
  const int t = tid & 63;
  const int cg = tid >> 6;
  const int kbase = cg * 16;

  #pragma unroll
  for (int q = 0; q < 16; ++q) As[q * 256 + tid] = Aw[q * 256 + tid];
  __syncthreads();

  double s[16];
  #pragma unroll
  for (int q = 0; q < 16; ++q) s[q] = 0.0;
  for (int i = 0; i < DD; ++i) {
    const double at = (double)As[i * DD + t];
    const float* ak = As + i * DD + kbase;
    #pragma unroll
    for (int q = 0; q < 16; ++q) s[q] += at * (double)ak[q];
  }
  double wreg[16];
  #pragma unroll
  for (int q = 0; q < 16; ++q) {
    const int k = kbase + q;
    const double w = ((t == k) ? 0.9 : 0.0) - s[q]
                   + (double)Bw[t * DD + k] - (double)Bw[k * DD + t];
    wreg[q] = w;
    Wss[k * DD + t] = (float)w;
  }
  __syncthreads();

  #pragma unroll
  for (int q = 0; q < 16; ++q) {
    const int k = kbase + q;
    MT[k][t]      = ((t == k) ? 2.0 : 0.0) - wreg[q];
    MT[DD + k][t] = (t == k) ? 1.0 : 0.0;
  }
  __syncthreads();

  for (int c = 0; c < DD; ++c) {
    const double p = 1.0 / MT[c][c];
    const double f = (t == c) ? 0.0 : MT[c][t];
    __syncthreads();
    if (tid < 2 * DD) MT[tid][c] *= p;
    __syncthreads();
    if (t != c) {
      #pragma unroll 4
      for (int jj = 0; jj < 32; ++jj) {
        const int j = cg * 32 + jj;
        MT[j][t] -= f * MT[j][c];
      }
    }
    __syncthreads();
  }

  #pragma unroll
  for (int q = 0; q < 16; ++q) {
    const int k = kbase + q;
    const float wi = (float)MT[DD + k][t];
    Winvs[k * DD + t] = wi;
    Rms[k * DD + t]   = 2.0f * wi - ((k == t) ? 1.0f : 0.0f);
  }
}

// ---------------------------------------------------------------------------
// Fully fused solve: per wave 64 dims x 16 batch cols, barrier-free.
//   h = relu(W1 x^T + b1); bias = Uw h + Ub (kept in C/D regs);
//   c2 = 2 Winv bias; 49x u <- c2 + R^T|u|; zn = relu(W z + bias);
//   out = relu(zn) @ Pw^T + Pb (MFMA with zero-padded Pw).
// ---------------------------------------------------------------------------
__global__ __launch_bounds__(256) void k_solve(
    const float* __restrict__ x,  const float* __restrict__ b1,
    const float* __restrict__ Ub, const float* __restrict__ Pb,
    const float* __restrict__ mats, float* __restrict__ out) {
  __shared__ unsigned stp[64 * STW];   // packed state, one 76-word column per batch col
  const float* W1s   = mats + OFF_W1S;
  const float* Uws   = mats + OFF_UWS;
  const float* Winvs = mats + OFF_WINVS;
  const float* Rms   = mats + OFF_RMS;
  const float* Wss   = mats + OFF_WSS;
  const float* PwsA  = mats + OFF_PWS;
  const int tid  = threadIdx.x;
  const int lane = tid & 63, wv = tid >> 6;
  const int l15  = lane & 15, kg = lane >> 4;
  const int ccol = wv * 16 + l15;
  const size_t ncol = (size_t)blockIdx.x * 64 + ccol;
  unsigned* stc = stp + ccol * STW;

  // R^T fragments resident in registers for all iterations
  bf16x8 rFh[4][2], rFl[4][2];
  #pragma unroll
  for (int rt = 0; rt < 4; ++rt)
    #pragma unroll
    for (int ki = 0; ki < 2; ++ki)
      build_a16(Rms, DD, 16*rt + l15, 32*ki + 8*kg, 1.0f, rFh[rt][ki], rFl[rt][ki]);

  // ---- h = relu(W1 x^T + b1): B from x directly (same slot map -> pi-cancel)
  f32x4 hC[4];
  #pragma unroll
  for (int rt = 0; rt < 4; ++rt)
    hC[rt] = *reinterpret_cast<const f32x4*>(b1 + 16*rt + 4*kg);
  #pragma unroll
  for (int ki = 0; ki < 4; ++ki) {                 // K = 128
    const float* xp = x + ncol * INF + 32*ki + 8*kg;
    float bv[8];
    #pragma unroll
    for (int s = 0; s < 8; ++s) bv[s] = xp[s];
    bf16x8 Bh, Bl; build_b8(bv, Bh, Bl);
    #pragma unroll
    for (int rt = 0; rt < 4; ++rt) {
      bf16x8 ah, al;
      build_a16(W1s, DD, 16*rt + l15, 32*ki + 8*kg, 1.0f, ah, al);
      hC[rt] = MF16(ah, Bh, hC[rt]);
      hC[rt] = MF16(ah, Bl, hC[rt]);
      hC[rt] = MF16(al, Bh, hC[rt]);
    }
  }
  #pragma unroll
  for (int rt = 0; rt < 4; ++rt) store_pk<2>(stc, kg, rt, hC[rt]);   // relu(h)

  // ---- bias = Uw h + Ub  (kept in regs for the zn C-init)
  f32x4 biasC[4];
  #pragma unroll
  for (int rt = 0; rt < 4; ++rt)
    biasC[rt] = *reinterpret_cast<const f32x4*>(Ub + 16*rt + 4*kg);
  product3(biasC, Uws, 1.0f, stc, kg, l15);
  #pragma unroll
  for (int rt = 0; rt < 4; ++rt) store_pk<0>(stc, kg, rt, biasC[rt]);

  // ---- c2 = 2 Winv bias
  f32x4 c2a[4];
  #pragma unroll
  for (int rt = 0; rt < 4; ++rt) c2a[rt] = (f32x4){0.f, 0.f, 0.f, 0.f};
  product3(c2a, Winvs, 2.0f, stc, kg, l15);
  #pragma unroll
  for (int rt = 0; rt < 4; ++rt) store_pk<1>(stc, kg, rt, c2a[rt]);  // |u1| = |c2|

  // ---- u_{k+1} = c2 + R^T|u_k| : 48 abs iterations, then 1 relu
  f32x4 u[4];
  #pragma unroll 1
  for (int it = 0; it < NITER - 2; ++it) {
    #pragma unroll
    for (int ki = 0; ki < 2; ++ki) {
      FragU bh, bl;
      bh.u = *reinterpret_cast<const uint4*>(stc + 16*ki + 4*kg);
      bl.u = *reinterpret_cast<const uint4*>(stc + 32 + 16*ki + 4*kg);
      #pragma unroll
      for (int rt = 0; rt < 4; ++rt) {
        f32x4 base = (ki == 0) ? c2a[rt] : u[rt];
        u[rt] = MF16(rFh[rt][ki], bh.f, base);
        u[rt] = MF16(rFh[rt][ki], bl.f, u[rt]);
        u[rt] = MF16(rFl[rt][ki], bh.f, u[rt]);
      }
    }
    #pragma unroll
    for (int rt = 0; rt < 4; ++rt) store_pk<1>(stc, kg, rt, u[rt]);
  }
  // final PR step -> u50; state = z = relu(u50)
  #pragma unroll
  for (int ki = 0; ki < 2; ++ki) {
    FragU bh, bl;
    bh.u = *reinterpret_cast<const uint4*>(stc + 16*ki + 4*kg);
    bl.u = *reinterpret_cast<const uint4*>(stc + 32 + 16*ki + 4*kg);
    #pragma unroll
    for (int rt = 0; rt < 4; ++rt) {
      f32x4 base = (ki == 0) ? c2a[rt] : u[rt];
      u[rt] = MF16(rFh[rt][ki], bh.f, base);
      u[rt] = MF16(rFh[rt][ki], bl.f, u[rt]);
      u[rt] = MF16(rFl[rt][ki], bh.f, u[rt]);
    }
  }
  #pragma unroll
  for (int rt = 0; rt < 4; ++rt) store_pk<2>(stc, kg, rt, u[rt]);

  // ---- zn = relu(W z + bias), C-init = biasC (regs)
  f32x4 zn[4];
  #pragma unroll
  for (int rt = 0; rt < 4; ++rt) zn[rt] = biasC[rt];
  product3(zn, Wss, 1.0f, stc, kg, l15);
  #pragma unroll
  for (int rt = 0; rt < 4; ++rt) store_pk<2>(stc, kg, rt, zn[rt]);   // relu(zn)

  // ---- out = relu(zn) @ Pw^T + Pb via MFMA (A rows 8..15 are zero)
  f32x4 oC = (f32x4){0.f, 0.f, 0.f, 0.f};
  if (kg < 2) {
    const float4 pb = *reinterpret_cast<const float4*>(Pb + 4*kg);
    oC[0] = pb.x; oC[1] = pb.y; oC[2] = pb.z; oC[3] = pb.w;
  }
  #pragma unroll
  for (int ki = 0; ki < 2; ++ki) {
    FragU bh, bl;
    bh.u = *reinterpret_cast<const uint4*>(stc + 16*ki + 4*kg);
    bl.u = *reinterpret_cast<const uint4*>(stc + 32 + 16*ki + 4*kg);
    bf16x8 ah, al;
    build_a16(PwsA, 16, l15, 32*ki + 8*kg, 1.0f, ah, al);
    oC = MF16(ah, bh.f, oC);
    oC = MF16(ah, bl.f, oC);
    oC = MF16(al, bh.f, oC);
  }
  if (kg < 2) {
    float4* op = reinterpret_cast<float4*>(out + ncol * NOUT + 4*kg);
    *op = make_float4(oC[0], oC[1], oC[2], oC[3]);
  }
}

extern "C" void kernel_launch(void* const* d_in, const int* in_sizes, int n_in,
                              void* d_out, int out_size, void* d_ws, size_t ws_size,
                              hipStream_t stream) {
  const float* x  = (const float*)d_in[0];
  const float* W1 = (const float*)d_in[1];
  const float* b1 = (const float*)d_in[2];
  const float* Uw = (const float*)d_in[3];
  const float* Ub = (const float*)d_in[4];
  const float* Aw = (const float*)d_in[5];
  const float* Bw = (const float*)d_in[6];
  const float* Pw = (const float*)d_in[7];
  const float* Pb = (const float*)d_in[8];
  float* outp = (float*)d_out;
  float* mats = (float*)d_ws;                     // ~100 KB of streamed matrices

  k_layout<<<52, 256, 0, stream>>>(W1, Uw, Pw, mats);
  k_inv   <<<1, 256, 0, stream>>>(Aw, Bw, mats);
  k_solve <<<BROWS/64, 256, 0, stream>>>(x, b1, Ub, Pb, mats, outp);
}